// Round 1
// baseline (115.603 us; speedup 1.0000x reference)
//
#include <hip/hip_runtime.h>
#include <cstdint>

#define DT_F    0.01f
#define NB      16      // batch
#define T_SEQ   2048    // sequence
#define DD      1024    // d_in
#define NS      128     // n_state
#define CHUNK   128     // scan chunk length
#define NCH     16      // chunks = T_SEQ/CHUNK

using f32x4  = __attribute__((ext_vector_type(4))) float;
using bf16x8 = __attribute__((ext_vector_type(8))) short;
using fl4    = __attribute__((ext_vector_type(4))) float;

__device__ __forceinline__ unsigned short f2bf(float f) {
  union { float f; unsigned u; } v; v.f = f;
  unsigned r = v.u + 0x7fffu + ((v.u >> 16) & 1u);   // RNE
  return (unsigned short)(r >> 16);
}

// ---------------------------------------------------------------------------
// prep: a_disc (f32 re/im) and B_disc (bf16, rows 0..127 = re, 128..255 = im)
//   denom = 1 - dt/2*a ;  a_disc = (1+dt/2*a)/denom ; B_disc = sqrt(dt)*B/denom
// grid: 128 blocks (one per n), 128 threads
// ---------------------------------------------------------------------------
__global__ void prep(const float* __restrict__ Ar, const float* __restrict__ Ai,
                     const float* __restrict__ B, unsigned short* __restrict__ W,
                     float* __restrict__ ad) {
  const int n = blockIdx.x;
  const int tid = threadIdx.x;
  const float ar = Ar[n], ai = Ai[n];
  const float dr = 1.f - 0.5f * DT_F * ar;
  const float di = -0.5f * DT_F * ai;
  const float inv = 1.f / (dr * dr + di * di);
  const float nr = 1.f + 0.5f * DT_F * ar;
  const float ni = 0.5f * DT_F * ai;
  if (tid == 0) {
    ad[n]      = (nr * dr + ni * di) * inv;   // Re(a_disc)
    ad[NS + n] = (ni * dr - nr * di) * inv;   // Im(a_disc)
  }
  const float s  = sqrtf(DT_F);
  const float cr = s * dr * inv;              // Re(sqrt(dt)/denom)
  const float ci = -s * di * inv;             // Im(sqrt(dt)/denom)
  for (int d = tid; d < DD; d += blockDim.x) {
    const float b = B[(size_t)n * DD + d];
    W[(size_t)n * DD + d]        = f2bf(b * cr);
    W[(size_t)(NS + n) * DD + d] = f2bf(b * ci);
  }
}

// C (1024x128 f32) -> bf16
__global__ void cvtC(const float* __restrict__ C, unsigned short* __restrict__ Cb) {
  const int i = blockIdx.x * blockDim.x + threadIdx.x;  // grid covers 131072
  Cb[i] = f2bf(C[i]);
}

// ---------------------------------------------------------------------------
// NT bf16 GEMM: Cout[M x N] (f32) = A[M x K] * Bw[N x K]^T
// 128x128 tile, 4 waves (2x2 of 64x64), BK=64, mfma_f32_16x16x32_bf16.
// AF32: A is f32 in global, converted to bf16 during staging.
// blockIdx.x = bm, blockIdx.y = bn
// ---------------------------------------------------------------------------
template<bool AF32>
__global__ __launch_bounds__(256) void gemm_nt(const void* __restrict__ Aptr,
                                               const unsigned short* __restrict__ Bw,
                                               float* __restrict__ Cout,
                                               int M, int N, int K) {
  __shared__ __align__(16) unsigned short As[128 * 64];
  __shared__ __align__(16) unsigned short Bs[128 * 64];
  const int tid  = threadIdx.x;
  const int lane = tid & 63;
  const int wave = tid >> 6;
  const int bm = blockIdx.x, bn = blockIdx.y;
  const int rowA0 = bm * 128, colB0 = bn * 128;
  const int wm = (wave >> 1) * 64, wn = (wave & 1) * 64;

  f32x4 acc[4][4];
  const f32x4 zero = {0.f, 0.f, 0.f, 0.f};
#pragma unroll
  for (int i = 0; i < 4; ++i)
#pragma unroll
    for (int j = 0; j < 4; ++j) acc[i][j] = zero;

  const int srow = tid >> 3;          // 0..31
  const int scol = (tid & 7) * 8;     // 0..56

  for (int k0 = 0; k0 < K; k0 += 64) {
    __syncthreads();
#pragma unroll
    for (int it = 0; it < 4; ++it) {
      const int r = it * 32 + srow;
      if constexpr (AF32) {
        const float* ga = (const float*)Aptr + (size_t)(rowA0 + r) * K + k0 + scol;
        fl4 v0 = *(const fl4*)ga;
        fl4 v1 = *(const fl4*)(ga + 4);
        bf16x8 pk;
        pk[0] = (short)f2bf(v0[0]); pk[1] = (short)f2bf(v0[1]);
        pk[2] = (short)f2bf(v0[2]); pk[3] = (short)f2bf(v0[3]);
        pk[4] = (short)f2bf(v1[0]); pk[5] = (short)f2bf(v1[1]);
        pk[6] = (short)f2bf(v1[2]); pk[7] = (short)f2bf(v1[3]);
        *(bf16x8*)&As[r * 64 + scol] = pk;
      } else {
        const unsigned short* ga = (const unsigned short*)Aptr + (size_t)(rowA0 + r) * K + k0 + scol;
        *(bf16x8*)&As[r * 64 + scol] = *(const bf16x8*)ga;
      }
      const unsigned short* gb = Bw + (size_t)(colB0 + r) * K + k0 + scol;
      *(bf16x8*)&Bs[r * 64 + scol] = *(const bf16x8*)gb;
    }
    __syncthreads();
#pragma unroll
    for (int ks = 0; ks < 2; ++ks) {
      bf16x8 af[4], bfr[4];
#pragma unroll
      for (int i = 0; i < 4; ++i)
        af[i] = *(const bf16x8*)&As[(wm + i * 16 + (lane & 15)) * 64 + ks * 32 + (lane >> 4) * 8];
#pragma unroll
      for (int j = 0; j < 4; ++j)
        bfr[j] = *(const bf16x8*)&Bs[(wn + j * 16 + (lane & 15)) * 64 + ks * 32 + (lane >> 4) * 8];
#pragma unroll
      for (int i = 0; i < 4; ++i)
#pragma unroll
        for (int j = 0; j < 4; ++j)
          acc[i][j] = __builtin_amdgcn_mfma_f32_16x16x32_bf16(af[i], bfr[j], acc[i][j], 0, 0, 0);
    }
  }

  // C/D layout (verified): col = lane&15, row = (lane>>4)*4 + q
#pragma unroll
  for (int i = 0; i < 4; ++i) {
    const int r0 = rowA0 + wm + i * 16 + (lane >> 4) * 4;
#pragma unroll
    for (int j = 0; j < 4; ++j) {
      const int c = colB0 + wn + j * 16 + (lane & 15);
#pragma unroll
      for (int q = 0; q < 4; ++q)
        Cout[(size_t)(r0 + q) * N + c] = acc[i][j][q];
    }
  }
}

// ---------------------------------------------------------------------------
// scan_local: per (b, chunk) local complex scan with h0=0, in-place on Bu
// (cols 0..127 = re, 128..255 = im). Writes chunk-final h to F.
// grid (NCH, NB), 128 threads (one per n).
// ---------------------------------------------------------------------------
__global__ void scan_local(float* __restrict__ Bu, const float* __restrict__ ad,
                           float* __restrict__ F) {
  const int c = blockIdx.x, b = blockIdx.y;
  const int n = threadIdx.x;
  const float ar = ad[n], ai = ad[NS + n];
  float hr = 0.f, hi = 0.f;
  float* p = Bu + ((size_t)b * T_SEQ + (size_t)c * CHUNK) * 256;
#pragma unroll 8
  for (int t = 0; t < CHUNK; ++t) {
    const float br = p[t * 256 + n];
    const float bi = p[t * 256 + 128 + n];
    const float nr = fmaf(ar, hr, fmaf(-ai, hi, br));
    const float ni = fmaf(ar, hi, fmaf(ai, hr, bi));
    hr = nr; hi = ni;
    p[t * 256 + n] = hr;
    p[t * 256 + 128 + n] = hi;
  }
  F[((size_t)b * NCH + c) * 256 + n]       = hr;
  F[((size_t)b * NCH + c) * 256 + 128 + n] = hi;
}

// ---------------------------------------------------------------------------
// scan_fix: carry = scan of chunk finals (each block redundantly folds its
// predecessors, aL = a^CHUNK via squaring), then h_t = local_t + a^{t+1}*carry.
// Emits Re(h) as bf16 into Hs [m = b*T+t][n].
// ---------------------------------------------------------------------------
__global__ void scan_fix(const float* __restrict__ Bu, const float* __restrict__ F,
                         const float* __restrict__ ad, unsigned short* __restrict__ Hs) {
  const int c = blockIdx.x, b = blockIdx.y;
  const int n = threadIdx.x;
  const float ar = ad[n], ai = ad[NS + n];
  // aL = a_disc^128 (7 complex squarings)
  float alr = ar, ali = ai;
#pragma unroll
  for (int s = 0; s < 7; ++s) {
    const float tr = alr * alr - ali * ali;
    const float ti = 2.f * alr * ali;
    alr = tr; ali = ti;
  }
  float cr = 0.f, ci = 0.f;
  for (int cc = 0; cc < c; ++cc) {
    const float fr = F[((size_t)b * NCH + cc) * 256 + n];
    const float fi = F[((size_t)b * NCH + cc) * 256 + 128 + n];
    const float nr = fmaf(alr, cr, fmaf(-ali, ci, fr));
    const float ni = fmaf(alr, ci, fmaf(ali, cr, fi));
    cr = nr; ci = ni;
  }
  // g_t = a^{t+1} * carry
  float gr = ar * cr - ai * ci;
  float gi = ar * ci + ai * cr;
  const float* p = Bu + ((size_t)b * T_SEQ + (size_t)c * CHUNK) * 256;
  unsigned short* o = Hs + ((size_t)b * T_SEQ + (size_t)c * CHUNK) * 128;
#pragma unroll 8
  for (int t = 0; t < CHUNK; ++t) {
    const float hr = p[t * 256 + n] + gr;
    o[t * 128 + n] = f2bf(hr);
    const float ngr = ar * gr - ai * gi;
    const float ngi = ar * gi + ai * gr;
    gr = ngr; gi = ngi;
  }
}

// ---------------------------------------------------------------------------
extern "C" void kernel_launch(void* const* d_in, const int* in_sizes, int n_in,
                              void* d_out, int out_size, void* d_ws, size_t ws_size,
                              hipStream_t stream) {
  const float* u  = (const float*)d_in[0];
  const float* Ar = (const float*)d_in[1];
  const float* Ai = (const float*)d_in[2];
  const float* B  = (const float*)d_in[3];
  const float* C  = (const float*)d_in[4];
  float* y = (float*)d_out;
  char* ws = (char*)d_ws;

  // workspace layout (total ~41.3 MB)
  unsigned short* W  = (unsigned short*)(ws);                               // 512 KB  (B_disc bf16, 256x1024)
  unsigned short* Cb = (unsigned short*)(ws + (512 << 10));                 // 256 KB  (C bf16)
  float*          ad = (float*)(ws + (768 << 10));                          // 1 KB    (a_disc re/im)
  float*          Bu = (float*)(ws + (1 << 20));                            // 33.5 MB (Bu -> local h, complex f32)
  unsigned short* Hs = (unsigned short*)(ws + (1 << 20) + 33554432);        // 8 MB    (Re(h) bf16)
  float*          F  = (float*)(ws + (1 << 20) + 33554432 + 8388608);       // 256 KB  (chunk finals)

  prep<<<dim3(128), dim3(128), 0, stream>>>(Ar, Ai, B, W, ad);
  cvtC<<<dim3(512), dim3(256), 0, stream>>>(C, Cb);
  // Bu[m=b*T+t][0:128]=re, [128:256]=im ; M=32768, N=256, K=1024
  gemm_nt<true ><<<dim3(256, 2), dim3(256), 0, stream>>>(u, W, Bu, NB * T_SEQ, 2 * NS, DD);
  scan_local<<<dim3(NCH, NB), dim3(128), 0, stream>>>(Bu, ad, F);
  scan_fix  <<<dim3(NCH, NB), dim3(128), 0, stream>>>(Bu, F, ad, Hs);
  // y[m][d] = sum_n Hs[m][n] * C[d][n] ; M=32768, N=1024, K=128
  gemm_nt<false><<<dim3(256, 8), dim3(256), 0, stream>>>(Hs, Cb, y, NB * T_SEQ, DD, NS);
}

// Round 2
// 106.419 us; speedup vs baseline: 1.0863x; 1.0863x over previous
//
#include <hip/hip_runtime.h>
#include <cstdint>

#define DT_F    0.01f
#define NB      16      // batch
#define T_SEQ   2048    // sequence
#define DD      1024    // d_in
#define NS      128     // n_state
#define CHUNK   64      // scan chunk length
#define NCH     32      // chunks = T_SEQ/CHUNK

using f32x4  = __attribute__((ext_vector_type(4))) float;
using bf16x8 = __attribute__((ext_vector_type(8))) short;
using fl4    = __attribute__((ext_vector_type(4))) float;

#define AS1(p) ((const __attribute__((address_space(1))) void*)(p))
#define AS3(p) ((__attribute__((address_space(3))) void*)(p))

__device__ __forceinline__ unsigned short f2bf(float f) {
  union { float f; unsigned u; } v; v.f = f;
  unsigned r = v.u + 0x7fffu + ((v.u >> 16) & 1u);   // RNE
  return (unsigned short)(r >> 16);
}
__device__ __forceinline__ float bf2f(unsigned short s) {
  union { unsigned u; float f; } v; v.u = ((unsigned)s) << 16;
  return v.f;
}

// ---------------------------------------------------------------------------
// prep: a_disc (f32 re/im) and B_disc (bf16, rows 0..127 = re, 128..255 = im)
// ---------------------------------------------------------------------------
__global__ void prep(const float* __restrict__ Ar, const float* __restrict__ Ai,
                     const float* __restrict__ B, unsigned short* __restrict__ W,
                     float* __restrict__ ad) {
  const int n = blockIdx.x;
  const int tid = threadIdx.x;
  const float ar = Ar[n], ai = Ai[n];
  const float dr = 1.f - 0.5f * DT_F * ar;
  const float di = -0.5f * DT_F * ai;
  const float inv = 1.f / (dr * dr + di * di);
  const float nr = 1.f + 0.5f * DT_F * ar;
  const float ni = 0.5f * DT_F * ai;
  if (tid == 0) {
    ad[n]      = (nr * dr + ni * di) * inv;   // Re(a_disc)
    ad[NS + n] = (ni * dr - nr * di) * inv;   // Im(a_disc)
  }
  const float s  = sqrtf(DT_F);
  const float cr = s * dr * inv;              // Re(sqrt(dt)/denom)
  const float ci = -s * di * inv;             // Im(sqrt(dt)/denom)
  for (int d = tid; d < DD; d += blockDim.x) {
    const float b = B[(size_t)n * DD + d];
    W[(size_t)n * DD + d]        = f2bf(b * cr);
    W[(size_t)(NS + n) * DD + d] = f2bf(b * ci);
  }
}

__global__ void cvtC(const float* __restrict__ C, unsigned short* __restrict__ Cb) {
  const int i = blockIdx.x * blockDim.x + threadIdx.x;  // covers 131072
  Cb[i] = f2bf(C[i]);
}

// ---------------------------------------------------------------------------
// NT bf16 GEMM: Cout[M x N] = A[M x K] * Bw[N x K]^T
// 128x128 tile, 4 waves (2x2 of 64x64), BK=64, mfma_f32_16x16x32_bf16.
// AF32: A is f32 in global, converted to bf16 during reg-staging.
//       bf16 operands are staged via global_load_lds (width 16).
// OUT_BF16: epilogue stores bf16 instead of f32.
// ---------------------------------------------------------------------------
template<bool AF32, bool OUT_BF16>
__global__ __launch_bounds__(256) void gemm_nt(const void* __restrict__ Aptr,
                                               const unsigned short* __restrict__ Bw,
                                               void* __restrict__ Cout,
                                               int M, int N, int K) {
  __shared__ __align__(16) unsigned short As[128 * 64];
  __shared__ __align__(16) unsigned short Bs[128 * 64];
  const int tid  = threadIdx.x;
  const int lane = tid & 63;
  const int wave = tid >> 6;
  const int bm = blockIdx.x, bn = blockIdx.y;
  const int rowA0 = bm * 128, colB0 = bn * 128;
  const int wm = (wave >> 1) * 64, wn = (wave & 1) * 64;

  f32x4 acc[4][4];
  const f32x4 zero = {0.f, 0.f, 0.f, 0.f};
#pragma unroll
  for (int i = 0; i < 4; ++i)
#pragma unroll
    for (int j = 0; j < 4; ++j) acc[i][j] = zero;

  const int srow = tid >> 3;          // 0..31 (reg-stage pattern)
  const int scol = (tid & 7) * 8;     // 0..56

  for (int k0 = 0; k0 < K; k0 += 64) {
    __syncthreads();
    // --- B tile: global_load_lds, wave-partitioned, linear LDS dest ---
#pragma unroll
    for (int it = 0; it < 4; ++it) {
      const int rb = it * 32 + wave * 8 + (lane >> 3);
      const unsigned short* gb = Bw + (size_t)(colB0 + rb) * K + k0 + (lane & 7) * 8;
      __builtin_amdgcn_global_load_lds(AS1(gb), AS3(&Bs[(it * 32 + wave * 8) * 64]), 16, 0, 0);
    }
    // --- A tile ---
    if constexpr (AF32) {
#pragma unroll
      for (int it = 0; it < 4; ++it) {
        const int r = it * 32 + srow;
        const float* ga = (const float*)Aptr + (size_t)(rowA0 + r) * K + k0 + scol;
        fl4 v0 = *(const fl4*)ga;
        fl4 v1 = *(const fl4*)(ga + 4);
        bf16x8 pk;
        pk[0] = (short)f2bf(v0[0]); pk[1] = (short)f2bf(v0[1]);
        pk[2] = (short)f2bf(v0[2]); pk[3] = (short)f2bf(v0[3]);
        pk[4] = (short)f2bf(v1[0]); pk[5] = (short)f2bf(v1[1]);
        pk[6] = (short)f2bf(v1[2]); pk[7] = (short)f2bf(v1[3]);
        *(bf16x8*)&As[r * 64 + scol] = pk;
      }
    } else {
#pragma unroll
      for (int it = 0; it < 4; ++it) {
        const int ra = it * 32 + wave * 8 + (lane >> 3);
        const unsigned short* ga = (const unsigned short*)Aptr + (size_t)(rowA0 + ra) * K + k0 + (lane & 7) * 8;
        __builtin_amdgcn_global_load_lds(AS1(ga), AS3(&As[(it * 32 + wave * 8) * 64]), 16, 0, 0);
      }
    }
    __syncthreads();
#pragma unroll
    for (int ks = 0; ks < 2; ++ks) {
      bf16x8 af[4], bfr[4];
#pragma unroll
      for (int i = 0; i < 4; ++i)
        af[i] = *(const bf16x8*)&As[(wm + i * 16 + (lane & 15)) * 64 + ks * 32 + (lane >> 4) * 8];
#pragma unroll
      for (int j = 0; j < 4; ++j)
        bfr[j] = *(const bf16x8*)&Bs[(wn + j * 16 + (lane & 15)) * 64 + ks * 32 + (lane >> 4) * 8];
#pragma unroll
      for (int i = 0; i < 4; ++i)
#pragma unroll
        for (int j = 0; j < 4; ++j)
          acc[i][j] = __builtin_amdgcn_mfma_f32_16x16x32_bf16(af[i], bfr[j], acc[i][j], 0, 0, 0);
    }
  }

  // C/D layout: col = lane&15, row = (lane>>4)*4 + q
#pragma unroll
  for (int i = 0; i < 4; ++i) {
    const int r0 = rowA0 + wm + i * 16 + (lane >> 4) * 4;
#pragma unroll
    for (int j = 0; j < 4; ++j) {
      const int c = colB0 + wn + j * 16 + (lane & 15);
      if constexpr (OUT_BF16) {
        unsigned short* O = (unsigned short*)Cout;
#pragma unroll
        for (int q = 0; q < 4; ++q)
          O[(size_t)(r0 + q) * N + c] = f2bf(acc[i][j][q]);
      } else {
        float* O = (float*)Cout;
#pragma unroll
        for (int q = 0; q < 4; ++q)
          O[(size_t)(r0 + q) * N + c] = acc[i][j][q];
      }
    }
  }
}

// ---------------------------------------------------------------------------
// scan_local: per (b, chunk) local complex scan, IN PLACE on bf16 Bu
// (cols 0..127 = re, 128..255 = im). Chunk-final h (f32) -> F.
// grid (NCH, NB), 128 threads.
// ---------------------------------------------------------------------------
__global__ void scan_local(unsigned short* __restrict__ Bu, const float* __restrict__ ad,
                           float* __restrict__ F) {
  const int c = blockIdx.x, b = blockIdx.y;
  const int n = threadIdx.x;
  const float ar = ad[n], ai = ad[NS + n];
  float hr = 0.f, hi = 0.f;
  unsigned short* p = Bu + ((size_t)b * T_SEQ + (size_t)c * CHUNK) * 256;
#pragma unroll 8
  for (int t = 0; t < CHUNK; ++t) {
    const float br = bf2f(p[t * 256 + n]);
    const float bi = bf2f(p[t * 256 + 128 + n]);
    const float nr = fmaf(ar, hr, fmaf(-ai, hi, br));
    const float ni = fmaf(ar, hi, fmaf(ai, hr, bi));
    hr = nr; hi = ni;
    p[t * 256 + n]       = f2bf(hr);
    p[t * 256 + 128 + n] = f2bf(hi);
  }
  F[((size_t)b * NCH + c) * 256 + n]       = hr;
  F[((size_t)b * NCH + c) * 256 + 128 + n] = hi;
}

// ---------------------------------------------------------------------------
// scan_fix: redundantly fold predecessor chunk-finals into carry
// (aL = a^CHUNK via 6 squarings), then h_t = local_t + a^{t+1}*carry.
// Emits Re(h) bf16 into Hs [m][n].
// ---------------------------------------------------------------------------
__global__ void scan_fix(const unsigned short* __restrict__ Bu, const float* __restrict__ F,
                         const float* __restrict__ ad, unsigned short* __restrict__ Hs) {
  const int c = blockIdx.x, b = blockIdx.y;
  const int n = threadIdx.x;
  const float ar = ad[n], ai = ad[NS + n];
  float alr = ar, ali = ai;                 // a^CHUNK, log2(CHUNK)=6 squarings
#pragma unroll
  for (int s = 0; s < 6; ++s) {
    const float tr = alr * alr - ali * ali;
    const float ti = 2.f * alr * ali;
    alr = tr; ali = ti;
  }
  float cr = 0.f, ci = 0.f;
  for (int cc = 0; cc < c; ++cc) {
    const float fr = F[((size_t)b * NCH + cc) * 256 + n];
    const float fi = F[((size_t)b * NCH + cc) * 256 + 128 + n];
    const float nr = fmaf(alr, cr, fmaf(-ali, ci, fr));
    const float ni = fmaf(alr, ci, fmaf(ali, cr, fi));
    cr = nr; ci = ni;
  }
  float gr = ar * cr - ai * ci;             // g_t = a^{t+1} * carry
  float gi = ar * ci + ai * cr;
  const unsigned short* p = Bu + ((size_t)b * T_SEQ + (size_t)c * CHUNK) * 256;
  unsigned short* o = Hs + ((size_t)b * T_SEQ + (size_t)c * CHUNK) * 128;
#pragma unroll 8
  for (int t = 0; t < CHUNK; ++t) {
    const float hr = bf2f(p[t * 256 + n]) + gr;
    o[t * 128 + n] = f2bf(hr);
    const float ngr = ar * gr - ai * gi;
    const float ngi = ar * gi + ai * gr;
    gr = ngr; gi = ngi;
  }
}

// ---------------------------------------------------------------------------
extern "C" void kernel_launch(void* const* d_in, const int* in_sizes, int n_in,
                              void* d_out, int out_size, void* d_ws, size_t ws_size,
                              hipStream_t stream) {
  const float* u  = (const float*)d_in[0];
  const float* Ar = (const float*)d_in[1];
  const float* Ai = (const float*)d_in[2];
  const float* B  = (const float*)d_in[3];
  const float* C  = (const float*)d_in[4];
  float* y = (float*)d_out;
  char* ws = (char*)d_ws;

  // workspace layout (~26.7 MB)
  unsigned short* W  = (unsigned short*)(ws);                                // 512 KB (B_disc bf16)
  unsigned short* Cb = (unsigned short*)(ws + (512 << 10));                  // 256 KB (C bf16)
  float*          ad = (float*)(ws + (768 << 10));                           // 1 KB   (a_disc)
  unsigned short* Bu = (unsigned short*)(ws + (1 << 20));                    // 16.75 MB (Bu -> local h, complex bf16)
  unsigned short* Hs = (unsigned short*)(ws + (1 << 20) + 16777216);         // 8 MB   (Re(h) bf16)
  float*          F  = (float*)(ws + (1 << 20) + 16777216 + 8388608);        // 512 KB (chunk finals f32)

  prep<<<dim3(128), dim3(128), 0, stream>>>(Ar, Ai, B, W, ad);
  cvtC<<<dim3(512), dim3(256), 0, stream>>>(C, Cb);
  // Bu[m=b*T+t][0:128]=re, [128:256]=im ; M=32768, N=256, K=1024
  gemm_nt<true, true ><<<dim3(256, 2), dim3(256), 0, stream>>>(u, W, Bu, NB * T_SEQ, 2 * NS, DD);
  scan_local<<<dim3(NCH, NB), dim3(128), 0, stream>>>(Bu, ad, F);
  scan_fix  <<<dim3(NCH, NB), dim3(128), 0, stream>>>(Bu, F, ad, Hs);
  // y[m][d] = sum_n Hs[m][n] * Cb[d][n] ; M=32768, N=1024, K=128
  gemm_nt<false, false><<<dim3(256, 8), dim3(256), 0, stream>>>(Hs, Cb, y, NB * T_SEQ, DD, NS);
}

// Round 3
// 101.541 us; speedup vs baseline: 1.1385x; 1.0480x over previous
//
#include <hip/hip_runtime.h>
#include <cstdint>

#define DT_F    0.01f
#define NB      16      // batch
#define T_SEQ   2048    // sequence
#define DD      1024    // d_in
#define NS      128     // n_state
#define CHUNK   64      // scan chunk length
#define NCH     32      // chunks = T_SEQ/CHUNK

using f32x4  = __attribute__((ext_vector_type(4))) float;
using bf16x8 = __attribute__((ext_vector_type(8))) short;
using fl4    = __attribute__((ext_vector_type(4))) float;

#define AS1(p) ((const __attribute__((address_space(1))) void*)(p))
#define AS3(p) ((__attribute__((address_space(3))) void*)(p))

__device__ __forceinline__ unsigned short f2bf(float f) {
  union { float f; unsigned u; } v; v.f = f;
  unsigned r = v.u + 0x7fffu + ((v.u >> 16) & 1u);   // RNE
  return (unsigned short)(r >> 16);
}
__device__ __forceinline__ float bf2f(unsigned short s) {
  union { unsigned u; float f; } v; v.u = ((unsigned)s) << 16;
  return v.f;
}

// ---------------------------------------------------------------------------
// prep_all: blocks 0..511 convert C->bf16 (512*256 = 131072 elems);
// blocks 512..639 build a_disc + B_disc row n = blk-512.
// ---------------------------------------------------------------------------
__global__ void prep_all(const float* __restrict__ Ar, const float* __restrict__ Ai,
                         const float* __restrict__ B, const float* __restrict__ C,
                         unsigned short* __restrict__ W, unsigned short* __restrict__ Cb,
                         float* __restrict__ ad) {
  const int blk = blockIdx.x;
  const int tid = threadIdx.x;
  if (blk < 512) {
    const int i = blk * 256 + tid;
    Cb[i] = f2bf(C[i]);
    return;
  }
  const int n = blk - 512;
  const float ar = Ar[n], ai = Ai[n];
  const float dr = 1.f - 0.5f * DT_F * ar;
  const float di = -0.5f * DT_F * ai;
  const float inv = 1.f / (dr * dr + di * di);
  const float nr = 1.f + 0.5f * DT_F * ar;
  const float ni = 0.5f * DT_F * ai;
  if (tid == 0) {
    ad[n]      = (nr * dr + ni * di) * inv;   // Re(a_disc)
    ad[NS + n] = (ni * dr - nr * di) * inv;   // Im(a_disc)
  }
  const float s  = sqrtf(DT_F);
  const float cr = s * dr * inv;              // Re(sqrt(dt)/denom)
  const float ci = -s * di * inv;             // Im(sqrt(dt)/denom)
  for (int d = tid; d < DD; d += 256) {
    const float b = B[(size_t)n * DD + d];
    W[(size_t)n * DD + d]        = f2bf(b * cr);
    W[(size_t)(NS + n) * DD + d] = f2bf(b * ci);
  }
}

// ---------------------------------------------------------------------------
// NT bf16 GEMM: Cout[M x N] = A[M x K] * Bw[N x K]^T
// 128x128 tile, 4 waves (2x2 of 64x64), BK=64, mfma_f32_16x16x32_bf16.
// 1D grid with XCD-chunked swizzle: xcd = L&7 owns a contiguous bm strip;
// consecutive k on one XCD share the same A panel -> fetched once into its L2.
// AF32: A is f32, converted to bf16 during reg-staging (bf16 ops use
// global_load_lds width=16). OUT_BF16: store bf16.
// ---------------------------------------------------------------------------
template<bool AF32, bool OUT_BF16, int BN_CNT>
__global__ __launch_bounds__(256) void gemm_nt(const void* __restrict__ Aptr,
                                               const unsigned short* __restrict__ Bw,
                                               void* __restrict__ Cout,
                                               int M, int N, int K) {
  __shared__ __align__(16) unsigned short As[128 * 64];
  __shared__ __align__(16) unsigned short Bs[128 * 64];
  const int tid  = threadIdx.x;
  const int lane = tid & 63;
  const int wave = tid >> 6;

  const int L   = blockIdx.x;
  const int xcd = L & 7;
  const int k   = L >> 3;
  const int bmpx = (int)(gridDim.x >> 3) / BN_CNT;  // bm strip per XCD (=32 here)
  const int bm  = xcd * bmpx + k / BN_CNT;
  const int bn  = k % BN_CNT;

  const int rowA0 = bm * 128, colB0 = bn * 128;
  const int wm = (wave >> 1) * 64, wn = (wave & 1) * 64;

  f32x4 acc[4][4];
  const f32x4 zero = {0.f, 0.f, 0.f, 0.f};
#pragma unroll
  for (int i = 0; i < 4; ++i)
#pragma unroll
    for (int j = 0; j < 4; ++j) acc[i][j] = zero;

  const int srow = tid >> 3;          // 0..31 (reg-stage pattern)
  const int scol = (tid & 7) * 8;     // 0..56

  for (int k0 = 0; k0 < K; k0 += 64) {
    __syncthreads();
    // --- B tile: global_load_lds, wave-partitioned, linear LDS dest ---
#pragma unroll
    for (int it = 0; it < 4; ++it) {
      const int rb = it * 32 + wave * 8 + (lane >> 3);
      const unsigned short* gb = Bw + (size_t)(colB0 + rb) * K + k0 + (lane & 7) * 8;
      __builtin_amdgcn_global_load_lds(AS1(gb), AS3(&Bs[(it * 32 + wave * 8) * 64]), 16, 0, 0);
    }
    // --- A tile ---
    if constexpr (AF32) {
#pragma unroll
      for (int it = 0; it < 4; ++it) {
        const int r = it * 32 + srow;
        const float* ga = (const float*)Aptr + (size_t)(rowA0 + r) * K + k0 + scol;
        fl4 v0 = *(const fl4*)ga;
        fl4 v1 = *(const fl4*)(ga + 4);
        bf16x8 pk;
        pk[0] = (short)f2bf(v0[0]); pk[1] = (short)f2bf(v0[1]);
        pk[2] = (short)f2bf(v0[2]); pk[3] = (short)f2bf(v0[3]);
        pk[4] = (short)f2bf(v1[0]); pk[5] = (short)f2bf(v1[1]);
        pk[6] = (short)f2bf(v1[2]); pk[7] = (short)f2bf(v1[3]);
        *(bf16x8*)&As[r * 64 + scol] = pk;
      }
    } else {
#pragma unroll
      for (int it = 0; it < 4; ++it) {
        const int ra = it * 32 + wave * 8 + (lane >> 3);
        const unsigned short* ga = (const unsigned short*)Aptr + (size_t)(rowA0 + ra) * K + k0 + (lane & 7) * 8;
        __builtin_amdgcn_global_load_lds(AS1(ga), AS3(&As[(it * 32 + wave * 8) * 64]), 16, 0, 0);
      }
    }
    __syncthreads();
#pragma unroll
    for (int ks = 0; ks < 2; ++ks) {
      bf16x8 af[4], bfr[4];
#pragma unroll
      for (int i = 0; i < 4; ++i)
        af[i] = *(const bf16x8*)&As[(wm + i * 16 + (lane & 15)) * 64 + ks * 32 + (lane >> 4) * 8];
#pragma unroll
      for (int j = 0; j < 4; ++j)
        bfr[j] = *(const bf16x8*)&Bs[(wn + j * 16 + (lane & 15)) * 64 + ks * 32 + (lane >> 4) * 8];
#pragma unroll
      for (int i = 0; i < 4; ++i)
#pragma unroll
        for (int j = 0; j < 4; ++j)
          acc[i][j] = __builtin_amdgcn_mfma_f32_16x16x32_bf16(af[i], bfr[j], acc[i][j], 0, 0, 0);
    }
  }

  // C/D layout: col = lane&15, row = (lane>>4)*4 + q
#pragma unroll
  for (int i = 0; i < 4; ++i) {
    const int r0 = rowA0 + wm + i * 16 + (lane >> 4) * 4;
#pragma unroll
    for (int j = 0; j < 4; ++j) {
      const int c = colB0 + wn + j * 16 + (lane & 15);
      if constexpr (OUT_BF16) {
        unsigned short* O = (unsigned short*)Cout;
#pragma unroll
        for (int q = 0; q < 4; ++q)
          O[(size_t)(r0 + q) * N + c] = f2bf(acc[i][j][q]);
      } else {
        float* O = (float*)Cout;
#pragma unroll
        for (int q = 0; q < 4; ++q)
          O[(size_t)(r0 + q) * N + c] = acc[i][j][q];
      }
    }
  }
}

// ---------------------------------------------------------------------------
// scan_finals: per (b, chunk) local complex scan (h0=0) over bf16 Bu;
// writes ONLY the chunk-final h (f32) to F. grid (NCH, NB), 128 threads.
// ---------------------------------------------------------------------------
__global__ void scan_finals(const unsigned short* __restrict__ Bu,
                            const float* __restrict__ ad, float* __restrict__ F) {
  const int c = blockIdx.x, b = blockIdx.y;
  const int n = threadIdx.x;
  const float ar = ad[n], ai = ad[NS + n];
  float hr = 0.f, hi = 0.f;
  const unsigned short* p = Bu + ((size_t)b * T_SEQ + (size_t)c * CHUNK) * 256;
#pragma unroll 8
  for (int t = 0; t < CHUNK; ++t) {
    const float br = bf2f(p[t * 256 + n]);
    const float bi = bf2f(p[t * 256 + 128 + n]);
    const float nr = fmaf(ar, hr, fmaf(-ai, hi, br));
    const float ni = fmaf(ar, hi, fmaf(ai, hr, bi));
    hr = nr; hi = ni;
  }
  F[((size_t)b * NCH + c) * 256 + n]       = hr;
  F[((size_t)b * NCH + c) * 256 + 128 + n] = hi;
}

// ---------------------------------------------------------------------------
// scan_apply: fold predecessor finals into carry (aL = a^CHUNK, Horner),
// seed h = carry, re-run recurrence from original Bu, emit Re(h) bf16 -> Hs.
// ---------------------------------------------------------------------------
__global__ void scan_apply(const unsigned short* __restrict__ Bu,
                           const float* __restrict__ F, const float* __restrict__ ad,
                           unsigned short* __restrict__ Hs) {
  const int c = blockIdx.x, b = blockIdx.y;
  const int n = threadIdx.x;
  const float ar = ad[n], ai = ad[NS + n];
  float alr = ar, ali = ai;                 // a^CHUNK, log2(CHUNK)=6 squarings
#pragma unroll
  for (int s = 0; s < 6; ++s) {
    const float tr = alr * alr - ali * ali;
    const float ti = 2.f * alr * ali;
    alr = tr; ali = ti;
  }
  float hr = 0.f, hi = 0.f;                 // carry = h at end of chunk c-1
  for (int cc = 0; cc < c; ++cc) {
    const float fr = F[((size_t)b * NCH + cc) * 256 + n];
    const float fi = F[((size_t)b * NCH + cc) * 256 + 128 + n];
    const float nr = fmaf(alr, hr, fmaf(-ali, hi, fr));
    const float ni = fmaf(alr, hi, fmaf(ali, hr, fi));
    hr = nr; hi = ni;
  }
  const unsigned short* p = Bu + ((size_t)b * T_SEQ + (size_t)c * CHUNK) * 256;
  unsigned short* o = Hs + ((size_t)b * T_SEQ + (size_t)c * CHUNK) * 128;
#pragma unroll 8
  for (int t = 0; t < CHUNK; ++t) {
    const float br = bf2f(p[t * 256 + n]);
    const float bi = bf2f(p[t * 256 + 128 + n]);
    const float nr = fmaf(ar, hr, fmaf(-ai, hi, br));
    const float ni = fmaf(ar, hi, fmaf(ai, hr, bi));
    hr = nr; hi = ni;
    o[t * 128 + n] = f2bf(hr);
  }
}

// ---------------------------------------------------------------------------
extern "C" void kernel_launch(void* const* d_in, const int* in_sizes, int n_in,
                              void* d_out, int out_size, void* d_ws, size_t ws_size,
                              hipStream_t stream) {
  const float* u  = (const float*)d_in[0];
  const float* Ar = (const float*)d_in[1];
  const float* Ai = (const float*)d_in[2];
  const float* B  = (const float*)d_in[3];
  const float* C  = (const float*)d_in[4];
  float* y = (float*)d_out;
  char* ws = (char*)d_ws;

  // workspace layout (~26.7 MB)
  unsigned short* W  = (unsigned short*)(ws);                                // 512 KB (B_disc bf16)
  unsigned short* Cb = (unsigned short*)(ws + (512 << 10));                  // 256 KB (C bf16)
  float*          ad = (float*)(ws + (768 << 10));                           // 1 KB   (a_disc)
  unsigned short* Bu = (unsigned short*)(ws + (1 << 20));                    // 16.75 MB (complex bf16 Bu)
  unsigned short* Hs = (unsigned short*)(ws + (1 << 20) + 16777216);         // 8 MB   (Re(h) bf16)
  float*          F  = (float*)(ws + (1 << 20) + 16777216 + 8388608);        // 512 KB (chunk finals f32)

  prep_all<<<dim3(640), dim3(256), 0, stream>>>(Ar, Ai, B, C, W, Cb, ad);
  // Bu[m=b*T+t][0:128]=re, [128:256]=im ; M=32768, N=256, K=1024 ; 512 blocks
  gemm_nt<true, true, 2><<<dim3(512), dim3(256), 0, stream>>>(u, W, Bu, NB * T_SEQ, 2 * NS, DD);
  scan_finals<<<dim3(NCH, NB), dim3(128), 0, stream>>>(Bu, ad, F);
  scan_apply <<<dim3(NCH, NB), dim3(128), 0, stream>>>(Bu, F, ad, Hs);
  // y[m][d] = sum_n Hs[m][n] * Cb[d][n] ; M=32768, N=1024, K=128 ; 2048 blocks
  gemm_nt<false, false, 8><<<dim3(2048), dim3(256), 0, stream>>>(Hs, Cb, y, NB * T_SEQ, DD, NS);
}